// Round 1
// baseline (274.758 us; speedup 1.0000x reference)
//
#include <hip/hip_runtime.h>
#include <hip/hip_bf16.h>

// MHA forward: (q,k,v [2,4096,512] f32, mask [2,1,1,4096] i32, Wq/Wk/Wv/Wo [512,512] f32) -> [2,4096,512] f32
// Pipeline: bf16 proj GEMMs -> flash attention (online softmax, exp2 domain) -> bf16 out GEMM.

typedef __bf16 bf16;
typedef bf16 bf16x8 __attribute__((ext_vector_type(8)));
typedef bf16 bf16x4 __attribute__((ext_vector_type(4)));
typedef float f32x4 __attribute__((ext_vector_type(4)));

#define MFMA16(a, b, c) __builtin_amdgcn_mfma_f32_16x16x32_bf16(a, b, c, 0, 0, 0)

#if __has_builtin(__builtin_amdgcn_exp2f)
#define EXP2(x) __builtin_amdgcn_exp2f(x)
#else
#define EXP2(x) exp2f(x)
#endif

static constexpr int Bb = 2, Ss = 4096, Dd = 512, Hh = 8, DKc = 64;
static constexpr int Mrows = Bb * Ss;  // 8192
static constexpr float QSCALE = 0.125f * 1.44269504088896340736f;  // (1/sqrt(DK)) * log2(e)

// ---------------------------------------------------------------------------
// Projection GEMM: Y = X @ W^T  (M=8192, N=512, K=512), fp32 in, bf16 out
// scattered to [B][H][S][DK]. blockIdx.z selects (q,k,v); Q gets QSCALE.
// ---------------------------------------------------------------------------
__global__ __launch_bounds__(256) void gemm_proj(
    const float* __restrict__ Xq, const float* __restrict__ Xk, const float* __restrict__ Xv,
    const float* __restrict__ Wq, const float* __restrict__ Wk, const float* __restrict__ Wv,
    bf16* __restrict__ QKVh) {
  __shared__ bf16 sA[128][72];
  __shared__ bf16 sB[128][72];
  const int tid = threadIdx.x, lane = tid & 63, w = tid >> 6;
  const int l15 = lane & 15, g = lane >> 4;
  const int wr = w >> 1, wc = w & 1;
  const int z = blockIdx.z;
  const float* X = (z == 0) ? Xq : (z == 1) ? Xk : Xv;
  const float* W = (z == 0) ? Wq : (z == 1) ? Wk : Wv;
  bf16* Oh = QKVh + (size_t)z * ((size_t)Mrows * Dd);
  const float scale = (z == 0) ? QSCALE : 1.0f;
  const int m0 = blockIdx.x * 128, n0 = blockIdx.y * 128;

  f32x4 acc[4][4] = {};

  for (int k0 = 0; k0 < Dd; k0 += 64) {
    // stage A (X tile) and B (W tile): 128x64 f32 -> bf16 into padded LDS
    for (int i = 0; i < 8; i++) {
      int e = (tid + i * 256) * 4;
      int row = e >> 6, col = e & 63;
      float4 va = *(const float4*)&X[(size_t)(m0 + row) * Dd + k0 + col];
      float4 vb = *(const float4*)&W[(size_t)(n0 + row) * Dd + k0 + col];
      bf16x4 a4 = {(bf16)va.x, (bf16)va.y, (bf16)va.z, (bf16)va.w};
      bf16x4 b4 = {(bf16)vb.x, (bf16)vb.y, (bf16)vb.z, (bf16)vb.w};
      *(bf16x4*)&sA[row][col] = a4;
      *(bf16x4*)&sB[row][col] = b4;
    }
    __syncthreads();
    for (int ks = 0; ks < 2; ks++) {
      bf16x8 af[4], bfr[4];
      for (int mi = 0; mi < 4; mi++)
        af[mi] = *(const bf16x8*)&sA[wr * 64 + mi * 16 + l15][ks * 32 + g * 8];
      for (int ni = 0; ni < 4; ni++)
        bfr[ni] = *(const bf16x8*)&sB[wc * 64 + ni * 16 + l15][ks * 32 + g * 8];
      for (int mi = 0; mi < 4; mi++)
        for (int ni = 0; ni < 4; ni++)
          acc[mi][ni] = MFMA16(af[mi], bfr[ni], acc[mi][ni]);
    }
    __syncthreads();
  }
  // epilogue: scatter to [B][H][S][DK] bf16, with scale
  for (int mi = 0; mi < 4; mi++) {
    int mbase = m0 + wr * 64 + mi * 16 + g * 4;
    for (int ni = 0; ni < 4; ni++) {
      int n = n0 + wc * 64 + ni * 16 + l15;
      int h = n >> 6, dk = n & 63;
      for (int r = 0; r < 4; r++) {
        int mm = mbase + r;
        int b = mm >> 12, s = mm & 4095;
        Oh[(((size_t)(b * Hh + h)) * Ss + s) * DKc + dk] = (bf16)(acc[mi][ni][r] * scale);
      }
    }
  }
}

// ---------------------------------------------------------------------------
// Flash attention: per (bh, q-block of 64). 4 waves x 16 q-rows. KV tile 64.
// Online softmax in exp2 domain; l-sum via ones-column appended to V^T.
// ---------------------------------------------------------------------------
__global__ __launch_bounds__(256) void attn_fwd(
    const bf16* __restrict__ QKVh, const int* __restrict__ mask, bf16* __restrict__ AO) {
  __shared__ bf16 sK[64][72];
  __shared__ bf16 sVT[80][72];   // rows 0..63 = V^T(d,kv); row 64 = ones; 65..79 = zeros
  __shared__ bf16 sP[4][16][72]; // per-wave P tile
  __shared__ int sMask[64];

  const int tid = threadIdx.x, lane = tid & 63, w = tid >> 6;
  const int l15 = lane & 15, g = lane >> 4;
  const int bh = blockIdx.y, b = bh >> 3, h = bh & 7;
  const size_t hoff = (size_t)bh * Ss * DKc;
  const bf16* Qb = QKVh + hoff;
  const bf16* Kb = QKVh + (size_t)Mrows * Dd + hoff;
  const bf16* Vb = QKVh + 2 * (size_t)Mrows * Dd + hoff;
  const int q0 = blockIdx.x * 64 + w * 16;

  // Q fragments (A-operand), hoisted for the whole block
  bf16x8 qf[2];
  for (int ks = 0; ks < 2; ks++)
    qf[ks] = *(const bf16x8*)&Qb[(size_t)(q0 + l15) * DKc + ks * 32 + g * 8];

  // constant rows of sVT (ones column trick)
  for (int i = tid; i < 16 * 64; i += 256) {
    int rr = i >> 6, cc = i & 63;
    sVT[64 + rr][cc] = (rr == 0) ? (bf16)1.0f : (bf16)0.0f;
  }

  f32x4 o[5] = {};  // 4 d-tiles + lsum tile
  float mrow[4] = {-1e30f, -1e30f, -1e30f, -1e30f};

  for (int kv0 = 0; kv0 < Ss; kv0 += 64) {
    // stage K tile (row-major, padded)
    for (int c = tid; c < 512; c += 256) {
      int row = c >> 3, col = (c & 7) * 8;
      *(bf16x8*)&sK[row][col] = *(const bf16x8*)&Kb[(size_t)(kv0 + row) * DKc + col];
    }
    // stage V transposed: sVT[d][kv]
    for (int c = tid; c < 512; c += 256) {
      int kv = c & 63, d0 = (c >> 6) * 8;
      bf16x8 vv = *(const bf16x8*)&Vb[(size_t)(kv0 + kv) * DKc + d0];
      for (int j = 0; j < 8; j++) sVT[d0 + j][kv] = vv[j];
    }
    if (tid < 64) sMask[tid] = mask[b * Ss + kv0 + tid];
    __syncthreads();

    // S = Q K^T (already in exp2 domain via QSCALE)
    f32x4 sv[4] = {};
    for (int ks = 0; ks < 2; ks++) {
      for (int n = 0; n < 4; n++) {
        bf16x8 kf = *(const bf16x8*)&sK[n * 16 + l15][ks * 32 + g * 8];
        sv[n] = MFMA16(qf[ks], kf, sv[n]);
      }
    }
    // online softmax: row max (max over a superset incl. masked cols is harmless)
    float rm[4];
    for (int r = 0; r < 4; r++)
      rm[r] = fmaxf(fmaxf(sv[0][r], sv[1][r]), fmaxf(sv[2][r], sv[3][r]));
    for (int off = 1; off < 16; off <<= 1)
      for (int r = 0; r < 4; r++)
        rm[r] = fmaxf(rm[r], __shfl_xor(rm[r], off, 64));
    float fac[4];
    for (int r = 0; r < 4; r++) {
      float mn = fmaxf(mrow[r], rm[r]);
      fac[r] = EXP2(mrow[r] - mn);
      mrow[r] = mn;
    }
    for (int n = 0; n < 5; n++)
      for (int r = 0; r < 4; r++) o[n][r] *= fac[r];
    // P = exp2(S - m), masked keys -> 0, to LDS as bf16
    for (int n = 0; n < 4; n++) {
      int mv = sMask[n * 16 + l15];
      for (int r = 0; r < 4; r++) {
        float p = EXP2(sv[n][r] - mrow[r]);
        p = mv ? p : 0.0f;
        sP[w][g * 4 + r][n * 16 + l15] = (bf16)p;
      }
    }
    // O += P V (5th n-tile accumulates row-sum l into o[4] col 0)
    for (int ks = 0; ks < 2; ks++) {
      bf16x8 pf = *(const bf16x8*)&sP[w][l15][ks * 32 + g * 8];
      for (int n = 0; n < 5; n++) {
        bf16x8 vf = *(const bf16x8*)&sVT[n * 16 + l15][ks * 32 + g * 8];
        o[n] = MFMA16(pf, vf, o[n]);
      }
    }
    __syncthreads();
  }

  // normalize and store to AO [B][S][H*DK] bf16
  for (int r = 0; r < 4; r++) {
    float lsum = __shfl(o[4][r], (lane & 48), 64);  // col 64 lives at l15==0
    float inv = 1.0f / lsum;
    int q = q0 + g * 4 + r;
    bf16* dst = AO + ((size_t)(b * Ss + q)) * Dd + h * DKc;
    for (int n = 0; n < 4; n++) dst[n * 16 + l15] = (bf16)(o[n][r] * inv);
  }
}

// ---------------------------------------------------------------------------
// Output GEMM: out = AO @ Wo^T (M=8192, N=512, K=512), bf16 A, fp32 W, fp32 out
// ---------------------------------------------------------------------------
__global__ __launch_bounds__(256) void gemm_final(
    const bf16* __restrict__ AO, const float* __restrict__ Wo, float* __restrict__ out) {
  __shared__ bf16 sA[128][72];
  __shared__ bf16 sB[128][72];
  const int tid = threadIdx.x, lane = tid & 63, w = tid >> 6;
  const int l15 = lane & 15, g = lane >> 4;
  const int wr = w >> 1, wc = w & 1;
  const int m0 = blockIdx.x * 128, n0 = blockIdx.y * 128;

  f32x4 acc[4][4] = {};

  for (int k0 = 0; k0 < Dd; k0 += 64) {
    for (int i = 0; i < 4; i++) {
      int e = (tid + i * 256) * 8;
      int row = e >> 6, col = e & 63;
      *(bf16x8*)&sA[row][col] = *(const bf16x8*)&AO[(size_t)(m0 + row) * Dd + k0 + col];
    }
    for (int i = 0; i < 8; i++) {
      int e = (tid + i * 256) * 4;
      int row = e >> 6, col = e & 63;
      float4 vb = *(const float4*)&Wo[(size_t)(n0 + row) * Dd + k0 + col];
      bf16x4 b4 = {(bf16)vb.x, (bf16)vb.y, (bf16)vb.z, (bf16)vb.w};
      *(bf16x4*)&sB[row][col] = b4;
    }
    __syncthreads();
    for (int ks = 0; ks < 2; ks++) {
      bf16x8 af[4], bfr[4];
      for (int mi = 0; mi < 4; mi++)
        af[mi] = *(const bf16x8*)&sA[wr * 64 + mi * 16 + l15][ks * 32 + g * 8];
      for (int ni = 0; ni < 4; ni++)
        bfr[ni] = *(const bf16x8*)&sB[wc * 64 + ni * 16 + l15][ks * 32 + g * 8];
      for (int mi = 0; mi < 4; mi++)
        for (int ni = 0; ni < 4; ni++)
          acc[mi][ni] = MFMA16(af[mi], bfr[ni], acc[mi][ni]);
    }
    __syncthreads();
  }
  for (int mi = 0; mi < 4; mi++) {
    int mbase = m0 + wr * 64 + mi * 16 + g * 4;
    for (int ni = 0; ni < 4; ni++) {
      int n = n0 + wc * 64 + ni * 16 + l15;
      for (int r = 0; r < 4; r++)
        out[(size_t)(mbase + r) * Dd + n] = acc[mi][ni][r];
    }
  }
}

extern "C" void kernel_launch(void* const* d_in, const int* in_sizes, int n_in,
                              void* d_out, int out_size, void* d_ws, size_t ws_size,
                              hipStream_t stream) {
  const float* q = (const float*)d_in[0];
  const float* k = (const float*)d_in[1];
  const float* v = (const float*)d_in[2];
  const int* mask = (const int*)d_in[3];
  const float* Wq = (const float*)d_in[4];
  const float* Wk = (const float*)d_in[5];
  const float* Wv = (const float*)d_in[6];
  const float* Wo = (const float*)d_in[7];

  bf16* QKVh = (bf16*)d_ws;                          // 3 * 8192*512 bf16 = 25.2 MB
  bf16* AO = QKVh + 3 * (size_t)Mrows * Dd;          // 8192*512 bf16 = 8.4 MB
  float* out = (float*)d_out;

  gemm_proj<<<dim3(64, 4, 3), 256, 0, stream>>>(q, k, v, Wq, Wk, Wv, QKVh);
  attn_fwd<<<dim3(64, 16), 256, 0, stream>>>(QKVh, mask, AO);
  gemm_final<<<dim3(64, 4), 256, 0, stream>>>(AO, Wo, out);
}

// Round 2
// 187.718 us; speedup vs baseline: 1.4637x; 1.4637x over previous
//
#include <hip/hip_runtime.h>
#include <hip/hip_bf16.h>

// MHA forward. Pipeline:
//   gemm_proj: Q,K -> [B][H][S][DK] bf16 (Q pre-scaled into exp2 domain);
//              V    -> pre-masked V^T [B][H][DK][S] bf16
//   attn_fwd : swapped flash attention (S^T = K Q^T, O^T = V^T P^T), 32x32x16 MFMA,
//              in-register P via cvt_pk_bf16 + permlane32_swap (no P LDS round-trip)
//   gemm_final: AO @ Wo^T -> f32 out

typedef __bf16 bf16;
typedef bf16 bf16x8 __attribute__((ext_vector_type(8)));
typedef bf16 bf16x4 __attribute__((ext_vector_type(4)));
typedef float f32x4 __attribute__((ext_vector_type(4)));
typedef float f32x16 __attribute__((ext_vector_type(16)));
typedef unsigned int u32x2 __attribute__((ext_vector_type(2)));
typedef unsigned int u32x4 __attribute__((ext_vector_type(4)));

#define MFMA16(a, b, c) __builtin_amdgcn_mfma_f32_16x16x32_bf16(a, b, c, 0, 0, 0)
#define MFMA32(a, b, c) __builtin_amdgcn_mfma_f32_32x32x16_bf16(a, b, c, 0, 0, 0)

#if __has_builtin(__builtin_amdgcn_exp2f)
#define EXP2(x) __builtin_amdgcn_exp2f(x)
#else
#define EXP2(x) exp2f(x)
#endif

static constexpr int Bb = 2, Ss = 4096, Dd = 512, Hh = 8, DKc = 64;
static constexpr int Mrows = Bb * Ss;  // 8192
static constexpr float QSCALE = 0.125f * 1.44269504088896340736f;  // (1/sqrt(DK)) * log2(e)

__device__ inline unsigned cvtpk(float lo, float hi) {
  unsigned r;
  asm("v_cvt_pk_bf16_f32 %0, %1, %2" : "=v"(r) : "v"(lo), "v"(hi));
  return r;
}

// v_permlane32_swap: a' = [lanes0-31: a(own) | lanes32-63: b from lane-32]
//                    b' = [lanes0-31: a from lane+32 | lanes32-63: b(own)]
__device__ inline void plswap(unsigned& a, unsigned& b) {
#if __has_builtin(__builtin_amdgcn_permlane32_swap)
  u32x2 r = __builtin_amdgcn_permlane32_swap(a, b, false, false);
  a = r[0];
  b = r[1];
#else
  int hi = (threadIdx.x >> 5) & 1;
  unsigned pa = (unsigned)__shfl_xor((int)a, 32);
  unsigned pb = (unsigned)__shfl_xor((int)b, 32);
  unsigned na = hi ? pb : a;
  unsigned nb = hi ? b : pa;
  a = na;
  b = nb;
#endif
}

// ---------------------------------------------------------------------------
// Projection GEMM. z=0: Q (scaled) -> [B][H][S][DK]; z=1: K -> [B][H][S][DK];
// z=2: V -> masked V^T [B][H][DK][S] (computed as W_v · X^T via swapped frags).
// ---------------------------------------------------------------------------
__global__ __launch_bounds__(256) void gemm_proj(
    const float* __restrict__ Xq, const float* __restrict__ Xk, const float* __restrict__ Xv,
    const float* __restrict__ Wq, const float* __restrict__ Wk, const float* __restrict__ Wv,
    const int* __restrict__ mask, bf16* __restrict__ QKVh) {
  __shared__ bf16 sA[128][72];
  __shared__ bf16 sB[128][72];
  const int tid = threadIdx.x, lane = tid & 63, w = tid >> 6;
  const int l15 = lane & 15, g = lane >> 4;
  const int wr = w >> 1, wc = w & 1;
  const int z = blockIdx.z;
  const float* X = (z == 0) ? Xq : (z == 1) ? Xk : Xv;
  const float* W = (z == 0) ? Wq : (z == 1) ? Wk : Wv;
  const float scale = (z == 0) ? QSCALE : 1.0f;
  const int m0 = blockIdx.x * 128, n0 = blockIdx.y * 128;

  f32x4 acc[4][4] = {};

  for (int k0 = 0; k0 < Dd; k0 += 64) {
    for (int i = 0; i < 8; i++) {
      int e = (tid + i * 256) * 4;
      int row = e >> 6, col = e & 63;
      float4 va = *(const float4*)&X[(size_t)(m0 + row) * Dd + k0 + col];
      float4 vb = *(const float4*)&W[(size_t)(n0 + row) * Dd + k0 + col];
      bf16x4 a4 = {(bf16)va.x, (bf16)va.y, (bf16)va.z, (bf16)va.w};
      bf16x4 b4 = {(bf16)vb.x, (bf16)vb.y, (bf16)vb.z, (bf16)vb.w};
      *(bf16x4*)&sA[row][col] = a4;
      *(bf16x4*)&sB[row][col] = b4;
    }
    __syncthreads();
    // z<2: A=X (m-dim = s-rows), B=W (n-dim = features)
    // z=2: A=W (m-dim = features), B=X^T (n-dim = s-rows)
    bf16(*Am)[72] = (z == 2) ? sB : sA;
    bf16(*Bm)[72] = (z == 2) ? sA : sB;
    for (int ks = 0; ks < 2; ks++) {
      bf16x8 af[4], bfr[4];
      for (int mi = 0; mi < 4; mi++)
        af[mi] = *(const bf16x8*)&Am[wr * 64 + mi * 16 + l15][ks * 32 + g * 8];
      for (int ni = 0; ni < 4; ni++)
        bfr[ni] = *(const bf16x8*)&Bm[wc * 64 + ni * 16 + l15][ks * 32 + g * 8];
      for (int mi = 0; mi < 4; mi++)
        for (int ni = 0; ni < 4; ni++)
          acc[mi][ni] = MFMA16(af[mi], bfr[ni], acc[mi][ni]);
    }
    __syncthreads();
  }

  if (z < 2) {
    bf16* Oh = QKVh + (size_t)z * ((size_t)Mrows * Dd);
    for (int mi = 0; mi < 4; mi++) {
      int mbase = m0 + wr * 64 + mi * 16 + g * 4;
      for (int ni = 0; ni < 4; ni++) {
        int n = n0 + wc * 64 + ni * 16 + l15;
        int h = n >> 6, dk = n & 63;
        for (int r = 0; r < 4; r++) {
          int mm = mbase + r;
          int b = mm >> 12, s = mm & 4095;
          Oh[(((size_t)(b * Hh + h)) * Ss + s) * DKc + dk] = (bf16)(acc[mi][ni][r] * scale);
        }
      }
    }
  } else {
    // V^T: D[feat][s], masked
    bf16* VT = QKVh + 2 * (size_t)Mrows * Dd;
    int mv[4];
    for (int ni = 0; ni < 4; ni++) {
      int sg = m0 + wc * 64 + ni * 16 + l15;
      mv[ni] = mask[(sg >> 12) * Ss + (sg & 4095)];
    }
    for (int mi = 0; mi < 4; mi++) {
      int fbase = n0 + wr * 64 + mi * 16 + g * 4;
      for (int ni = 0; ni < 4; ni++) {
        int sg = m0 + wc * 64 + ni * 16 + l15;
        int b = sg >> 12, s = sg & 4095;
        for (int r = 0; r < 4; r++) {
          int feat = fbase + r;
          int h = feat >> 6, dk = feat & 63;
          VT[(((size_t)(b * Hh + h)) * DKc + dk) * Ss + s] =
              mv[ni] ? (bf16)acc[mi][ni][r] : (bf16)0.0f;
        }
      }
    }
  }
}

// ---------------------------------------------------------------------------
// Flash attention, swapped form. Block = 2 waves, each wave owns 32 q-columns.
// Per lane: one q column (l31); rows kv distributed per 32x32 C-layout.
// ---------------------------------------------------------------------------
__global__ __launch_bounds__(128) void attn_fwd(
    const bf16* __restrict__ QKVh, const int* __restrict__ mask, bf16* __restrict__ AO) {
  __shared__ bf16 sK[64][72];   // K tile  [kv][dk]
  __shared__ bf16 sVT[64][72];  // V^T tile [d][kv] (pre-masked)

  const int tid = threadIdx.x, lane = tid & 63, w = tid >> 6;
  const int l31 = lane & 31, g1 = lane >> 5;
  const int bh = blockIdx.y, b = bh >> 3, h = bh & 7;
  const size_t hoff = (size_t)bh * Ss * DKc;
  const bf16* Qb = QKVh + hoff;
  const bf16* Kb = QKVh + (size_t)Mrows * Dd + hoff;
  const bf16* VTb = QKVh + 2 * (size_t)Mrows * Dd + hoff;  // [dk][s]
  const int q = blockIdx.x * 64 + w * 32 + l31;  // this lane's q column

  // Q B-fragments (hoisted): B[k][col=q] = Q[q][k], k = ks*16 + g1*8 + j
  bf16x8 qf[4];
#pragma unroll
  for (int ks = 0; ks < 4; ks++)
    qf[ks] = *(const bf16x8*)&Qb[(size_t)q * DKc + ks * 16 + g1 * 8];

  f32x16 o0 = {}, o1 = {};
  float lsum = 0.0f, mrow = -1e30f;

  bf16x8 rk[4], rv[4];
  int mreg;
  auto prefetch = [&](int kv0n) {
#pragma unroll
    for (int i = 0; i < 4; i++) {
      int eid = tid + i * 128;
      int row = eid >> 3, col = (eid & 7) * 8;
      rk[i] = *(const bf16x8*)&Kb[(size_t)(kv0n + row) * DKc + col];
      rv[i] = *(const bf16x8*)&VTb[(size_t)row * Ss + kv0n + col];
    }
    mreg = mask[b * Ss + kv0n + lane];
  };
  prefetch(0);

  for (int kv0 = 0; kv0 < Ss; kv0 += 64) {
    __syncthreads();  // prev compute done; prefetched globals drained
#pragma unroll
    for (int i = 0; i < 4; i++) {
      int eid = tid + i * 128;
      int row = eid >> 3, col = (eid & 7) * 8;
      *(bf16x8*)&sK[row][col] = rk[i];
      *(bf16x8*)&sVT[row][col] = rv[i];
    }
    unsigned long long mb = __ballot(mreg != 0);
    __syncthreads();
    if (kv0 + 64 < Ss) prefetch(kv0 + 64);  // hides under compute

    // S^T = K · Q^T  (two 32-row m-tiles)
    f32x16 s0 = {}, s1 = {};
#pragma unroll
    for (int ks = 0; ks < 4; ks++) {
      bf16x8 k0 = *(const bf16x8*)&sK[l31][ks * 16 + g1 * 8];
      bf16x8 k1 = *(const bf16x8*)&sK[32 + l31][ks * 16 + g1 * 8];
      s0 = MFMA32(k0, qf[ks], s0);
      s1 = MFMA32(k1, qf[ks], s1);
    }

    // online softmax for this lane's q column (rows split with lane^32)
    float mx = s0[0];
#pragma unroll
    for (int r = 1; r < 16; r++) mx = fmaxf(mx, s0[r]);
#pragma unroll
    for (int r = 0; r < 16; r++) mx = fmaxf(mx, s1[r]);
    mx = fmaxf(mx, __shfl_xor(mx, 32));
    float mn = fmaxf(mrow, mx);
    float fac = EXP2(mrow - mn);
    mrow = mn;
    lsum *= fac;
#pragma unroll
    for (int r = 0; r < 16; r++) { o0[r] *= fac; o1[r] *= fac; }

    // P = exp2(S - m); masked kv excluded from l-sum only (V columns pre-zeroed)
    unsigned long long mbl = mb >> (4 * g1);
    float ts = 0.0f;
#pragma unroll
    for (int r = 0; r < 16; r++) {
      int row = (r & 3) + 8 * (r >> 2);  // + 4*g1 folded into mbl shift
      float p0 = EXP2(s0[r] - mn);
      float p1 = EXP2(s1[r] - mn);
      s0[r] = p0;
      s1[r] = p1;
      ts += ((mbl >> row) & 1ull) ? p0 : 0.0f;
      ts += ((mbl >> (row + 32)) & 1ull) ? p1 : 0.0f;
    }
    ts += __shfl_xor(ts, 32);
    lsum += ts;

    // Build PV B-fragments in-register: cvt_pk + permlane32_swap
    u32x4 pfw[4];
    {
      unsigned d0 = cvtpk(s0[0], s0[1]), d1 = cvtpk(s0[2], s0[3]);
      unsigned d2 = cvtpk(s0[4], s0[5]), d3 = cvtpk(s0[6], s0[7]);
      plswap(d0, d2);
      plswap(d1, d3);
      pfw[0] = (u32x4){d0, d1, d2, d3};
      unsigned e2 = cvtpk(s0[8], s0[9]), e3 = cvtpk(s0[10], s0[11]);
      unsigned e0 = cvtpk(s0[12], s0[13]), e1 = cvtpk(s0[14], s0[15]);
      plswap(e2, e0);
      plswap(e3, e1);
      pfw[1] = (u32x4){e2, e3, e0, e1};
    }
    {
      unsigned d0 = cvtpk(s1[0], s1[1]), d1 = cvtpk(s1[2], s1[3]);
      unsigned d2 = cvtpk(s1[4], s1[5]), d3 = cvtpk(s1[6], s1[7]);
      plswap(d0, d2);
      plswap(d1, d3);
      pfw[2] = (u32x4){d0, d1, d2, d3};
      unsigned e2 = cvtpk(s1[8], s1[9]), e3 = cvtpk(s1[10], s1[11]);
      unsigned e0 = cvtpk(s1[12], s1[13]), e1 = cvtpk(s1[14], s1[15]);
      plswap(e2, e0);
      plswap(e3, e1);
      pfw[3] = (u32x4){e2, e3, e0, e1};
    }

    // O^T += V^T · P^T
#pragma unroll
    for (int ks = 0; ks < 4; ks++) {
      bf16x8 pf = *(bf16x8*)&pfw[ks];
      bf16x8 v0 = *(const bf16x8*)&sVT[l31][ks * 16 + g1 * 8];
      bf16x8 v1 = *(const bf16x8*)&sVT[32 + l31][ks * 16 + g1 * 8];
      o0 = MFMA32(v0, pf, o0);
      o1 = MFMA32(v1, pf, o1);
    }
  }

  // normalize, store O^T column -> AO[b][q][h*64 + d]
  float inv = 1.0f / lsum;
  bf16* dst = AO + ((size_t)(b * Ss + q)) * Dd + h * DKc;
#pragma unroll
  for (int qd = 0; qd < 4; qd++) {
    bf16x4 a, c;
#pragma unroll
    for (int j = 0; j < 4; j++) {
      a[j] = (bf16)(o0[qd * 4 + j] * inv);
      c[j] = (bf16)(o1[qd * 4 + j] * inv);
    }
    *(bf16x4*)&dst[8 * qd + 4 * g1] = a;
    *(bf16x4*)&dst[32 + 8 * qd + 4 * g1] = c;
  }
}

// ---------------------------------------------------------------------------
// Output GEMM: out = AO @ Wo^T (M=8192, N=512, K=512), bf16 A, fp32 W, fp32 out
// ---------------------------------------------------------------------------
__global__ __launch_bounds__(256) void gemm_final(
    const bf16* __restrict__ AO, const float* __restrict__ Wo, float* __restrict__ out) {
  __shared__ bf16 sA[128][72];
  __shared__ bf16 sB[128][72];
  const int tid = threadIdx.x, lane = tid & 63, w = tid >> 6;
  const int l15 = lane & 15, g = lane >> 4;
  const int wr = w >> 1, wc = w & 1;
  const int m0 = blockIdx.x * 128, n0 = blockIdx.y * 128;

  f32x4 acc[4][4] = {};

  for (int k0 = 0; k0 < Dd; k0 += 64) {
    for (int i = 0; i < 4; i++) {
      int e = (tid + i * 256) * 8;
      int row = e >> 6, col = e & 63;
      *(bf16x8*)&sA[row][col] = *(const bf16x8*)&AO[(size_t)(m0 + row) * Dd + k0 + col];
    }
    for (int i = 0; i < 8; i++) {
      int e = (tid + i * 256) * 4;
      int row = e >> 6, col = e & 63;
      float4 vb = *(const float4*)&Wo[(size_t)(n0 + row) * Dd + k0 + col];
      bf16x4 b4 = {(bf16)vb.x, (bf16)vb.y, (bf16)vb.z, (bf16)vb.w};
      *(bf16x4*)&sB[row][col] = b4;
    }
    __syncthreads();
    for (int ks = 0; ks < 2; ks++) {
      bf16x8 af[4], bfr[4];
      for (int mi = 0; mi < 4; mi++)
        af[mi] = *(const bf16x8*)&sA[wr * 64 + mi * 16 + l15][ks * 32 + g * 8];
      for (int ni = 0; ni < 4; ni++)
        bfr[ni] = *(const bf16x8*)&sB[wc * 64 + ni * 16 + l15][ks * 32 + g * 8];
      for (int mi = 0; mi < 4; mi++)
        for (int ni = 0; ni < 4; ni++)
          acc[mi][ni] = MFMA16(af[mi], bfr[ni], acc[mi][ni]);
    }
    __syncthreads();
  }
  for (int mi = 0; mi < 4; mi++) {
    int mbase = m0 + wr * 64 + mi * 16 + g * 4;
    for (int ni = 0; ni < 4; ni++) {
      int n = n0 + wc * 64 + ni * 16 + l15;
      for (int r = 0; r < 4; r++)
        out[(size_t)(mbase + r) * Dd + n] = acc[mi][ni][r];
    }
  }
}

extern "C" void kernel_launch(void* const* d_in, const int* in_sizes, int n_in,
                              void* d_out, int out_size, void* d_ws, size_t ws_size,
                              hipStream_t stream) {
  const float* q = (const float*)d_in[0];
  const float* k = (const float*)d_in[1];
  const float* v = (const float*)d_in[2];
  const int* mask = (const int*)d_in[3];
  const float* Wq = (const float*)d_in[4];
  const float* Wk = (const float*)d_in[5];
  const float* Wv = (const float*)d_in[6];
  const float* Wo = (const float*)d_in[7];

  bf16* QKVh = (bf16*)d_ws;                  // Q, K, V^T: 3 * 8192*512 bf16
  bf16* AO = QKVh + 3 * (size_t)Mrows * Dd;  // 8192*512 bf16
  float* out = (float*)d_out;

  gemm_proj<<<dim3(64, 4, 3), 256, 0, stream>>>(q, k, v, Wq, Wk, Wv, mask, QKVh);
  attn_fwd<<<dim3(64, 16), 128, 0, stream>>>(QKVh, mask, AO);
  gemm_final<<<dim3(64, 4), 256, 0, stream>>>(AO, Wo, out);
}